// Round 1
// baseline (153.876 us; speedup 1.0000x reference)
//
#include <hip/hip_runtime.h>

// filtfilt butter(4,0.2), 512 rows x T=32768 fp32.
//  - reference's scale/unscale is linear-homogeneous -> cancels exactly -> skipped.
//  - poles |p|max ~0.796: fwd warm-up 32 (7e-4 abs), bwd warm-up 28 (~5e-3); thr 7e-2.
//  - R4 -> R5: kC 64 -> 32. The R4 kernel was latency-bound (VALUBusy 25%, HBM 33%,
//    occupancy 24%): grid 4096 waves = only 16 waves/CU even though VGPR=56 permits
//    the 8-waves/SIMD quantum. kC=32 doubles the grid to 8192 waves = 32/CU
//    (2048 blocks x 256 thr = 8 blocks/CU). +41% VALU work (warm-up amortized over
//    32 not 64 outputs) but VALU issue floor (~6 us) stays far below the ~21 us
//    HBM floor; DRAM traffic unchanged (warm-up reads = neighbors' main data, L1/L2 hit).
//  - forward intermediate held ENTIRELY IN REGISTERS as packed fp16 pairs.
//    CRITICAL: use native ext_vector_type(2) __fp16 (the return type of
//    __builtin_amdgcn_cvt_pkrtz), NOT __half2 (class type) — __half2 arrays fail
//    SROA and spill to scratch (R3: VGPR=56, WRITE_SIZE +70 MB scratch traffic).
//  - no LDS; __launch_bounds__(256,8) -> VGPR<=64 -> 8 waves/SIMD quantum holds.

typedef __fp16 h2 __attribute__((ext_vector_type(2)));

constexpr int kT   = 32768;
constexpr int kP   = 15;          // padlen
constexpr int kC   = 32;          // outputs per thread
constexpr int kWF  = 32;          // forward warm-up samples
constexpr int kNCh = kT / kC;     // 1024 chunks/row
constexpr int kTPB = 256;

#define B0 0.0048243445989025905f
#define B1 0.019297378395610362f
#define B2 0.028946067593415543f
#define B3 0.019297378395610362f
#define B4 0.0048243445989025905f
#define NA1 2.369513007182038f
#define NA2 (-2.3139884144002064f)
#define NA3 1.0546654058785661f
#define NA4 (-0.18737949236818502f)

// Direct-form II transposed step.
#define STEP(xv) do { \
    y  = fmaf(B0, (xv), z1); \
    z1 = fmaf(NA1, y, fmaf(B1, (xv), z2)); \
    z2 = fmaf(NA2, y, fmaf(B2, (xv), z3)); \
    z3 = fmaf(NA3, y, fmaf(B3, (xv), z4)); \
    z4 = fmaf(NA4, y, B4 * (xv)); \
} while (0)

// two steps -> one packed fp16 pair (v_cvt_pkrtz_f16_f32)
#define PACK2(va, vb, DST) do { \
    STEP(va); float _t = y; \
    STEP(vb); DST = __builtin_amdgcn_cvt_pkrtz(_t, y); \
} while (0)

__global__ __launch_bounds__(kTPB, 8)
void filtfilt_kernel(const float* __restrict__ x, float* __restrict__ out) {
    const int tid   = blockIdx.x * kTPB + threadIdx.x;
    const int row   = tid >> 10;            // /kNCh
    const int chunk = tid & (kNCh - 1);
    const bool last = (chunk == kNCh - 1);
    const float* __restrict__ xr = x + (size_t)row * kT;
    float* __restrict__ outr     = out + (size_t)row * kT;
    const int s = chunk * kC;

    h2 arc[kC / 2];   // 16: stored fwd samples (ext coords [s+15, s+47))
    h2 wu[14];        // bwd warm-up samples; last chunk: 15 right-ext tail

    float z1 = 0.f, z2 = 0.f, z3 = 0.f, z4 = 0.f, y;

    // ---------------- forward warm-up ----------------
    if (chunk == 0) {
        // exact: left odd-extension (ext 0..14), zero ICs
        const float4* x4 = (const float4*)xr;
        float4 a0 = x4[0], a1 = x4[1], a2 = x4[2], a3 = x4[3];
        float xa[16] = {a0.x,a0.y,a0.z,a0.w, a1.x,a1.y,a1.z,a1.w,
                        a2.x,a2.y,a2.z,a2.w, a3.x,a3.y,a3.z,a3.w};
        #pragma unroll
        for (int e = 0; e < kP; ++e) {
            float xv = fmaf(2.f, xa[0], -xa[kP - e]);
            STEP(xv);
        }
    } else {
        // approx: 32 samples from x[s-32, s), zero ICs (pole decay ~7e-4)
        const float4* wp = (const float4*)(xr + s - kWF);
        float4 w[8];
        #pragma unroll
        for (int i = 0; i < 8; ++i) w[i] = wp[i];
        #pragma unroll
        for (int i = 0; i < 8; ++i) {
            STEP(w[i].x); STEP(w[i].y); STEP(w[i].z); STEP(w[i].w);
        }
    }

    // ---------------- forward store: x[s, s+32) -> arc ----------------
    const float4* mp = (const float4*)(xr + s);
    {
        float4 c0 = mp[0], c1 = mp[1], c2 = mp[2], c3 = mp[3];
        float4 n0 = mp[4], n1 = mp[5], n2 = mp[6], n3 = mp[7];
        PACK2(c0.x, c0.y, arc[0]);  PACK2(c0.z, c0.w, arc[1]);
        PACK2(c1.x, c1.y, arc[2]);  PACK2(c1.z, c1.w, arc[3]);
        PACK2(c2.x, c2.y, arc[4]);  PACK2(c2.z, c2.w, arc[5]);
        PACK2(c3.x, c3.y, arc[6]);  PACK2(c3.z, c3.w, arc[7]);
        PACK2(n0.x, n0.y, arc[8]);  PACK2(n0.z, n0.w, arc[9]);
        PACK2(n1.x, n1.y, arc[10]); PACK2(n1.z, n1.w, arc[11]);
        PACK2(n2.x, n2.y, arc[12]); PACK2(n2.z, n2.w, arc[13]);
        PACK2(n3.x, n3.y, arc[14]); PACK2(n3.z, n3.w, arc[15]);
    }

    // ---------------- forward continue: bwd warm-up samples ----------------
    if (!last) {
        // 28 samples x[s+32, s+60)
        float4 d0 = mp[8],  d1 = mp[9],  d2 = mp[10], d3 = mp[11];
        float4 d4 = mp[12], d5 = mp[13], d6 = mp[14];
        PACK2(d0.x, d0.y, wu[0]);  PACK2(d0.z, d0.w, wu[1]);
        PACK2(d1.x, d1.y, wu[2]);  PACK2(d1.z, d1.w, wu[3]);
        PACK2(d2.x, d2.y, wu[4]);  PACK2(d2.z, d2.w, wu[5]);
        PACK2(d3.x, d3.y, wu[6]);  PACK2(d3.z, d3.w, wu[7]);
        PACK2(d4.x, d4.y, wu[8]);  PACK2(d4.z, d4.w, wu[9]);
        PACK2(d5.x, d5.y, wu[10]); PACK2(d5.z, d5.w, wu[11]);
        PACK2(d6.x, d6.y, wu[12]); PACK2(d6.z, d6.w, wu[13]);
    } else {
        // exact: 15 right-odd-extension samples (2x[T-1]-x[T-2-r])
        const float4* e4 = (const float4*)(xr + kT - 16);
        float4 b0 = e4[0], b1 = e4[1], b2 = e4[2], b3 = e4[3];
        float xa[16] = {b0.x,b0.y,b0.z,b0.w, b1.x,b1.y,b1.z,b1.w,
                        b2.x,b2.y,b2.z,b2.w, b3.x,b3.y,b3.z,b3.w};
        float pend = 0.f;
        #pragma unroll
        for (int r = 0; r < 15; ++r) {
            float xv = fmaf(2.f, xa[15], -xa[14 - r]);
            STEP(xv);
            if ((r & 1) == 0) pend = y;
            else wu[r >> 1] = __builtin_amdgcn_cvt_pkrtz(pend, y);
        }
        wu[7] = __builtin_amdgcn_cvt_pkrtz(pend, pend);  // r=14 in .x
    }

    // ---------------- backward warm-up (zero ICs; exact at signal end) ------
    z1 = z2 = z3 = z4 = 0.f;
    if (!last) {
        #pragma unroll
        for (int k = 13; k >= 0; --k) {
            float a = (float)wu[k].y; STEP(a);
            float b = (float)wu[k].x; STEP(b);
        }
    } else {
        { float a = (float)wu[7].x; STEP(a); }   // tail sample r=14
        #pragma unroll
        for (int k = 6; k >= 0; --k) {
            float a = (float)wu[k].y; STEP(a);
            float b = (float)wu[k].x; STEP(b);
        }
    }

    // ---------------- backward main: 32 outputs, descending ----------------
    float4* op = (float4*)(outr + s);
    #pragma unroll
    for (int gi = 7; gi >= 0; --gi) {
        float4 o; float v;
        v = (float)arc[2 * gi + 1].y; STEP(v); o.w = y;
        v = (float)arc[2 * gi + 1].x; STEP(v); o.z = y;
        v = (float)arc[2 * gi + 0].y; STEP(v); o.y = y;
        v = (float)arc[2 * gi + 0].x; STEP(v); o.x = y;
        op[gi] = o;
    }
}

extern "C" void kernel_launch(void* const* d_in, const int* in_sizes, int n_in,
                              void* d_out, int out_size, void* d_ws, size_t ws_size,
                              hipStream_t stream) {
    const float* x = (const float*)d_in[0];
    float* out     = (float*)d_out;
    const int rows   = in_sizes[0] / kT;          // 512
    const int blocks = rows * kNCh / kTPB;        // 2048
    filtfilt_kernel<<<blocks, kTPB, 0, stream>>>(x, out);
}